// Round 1
// baseline (942.757 us; speedup 1.0000x reference)
//
#include <hip/hip_runtime.h>
#include <hip/hip_bf16.h>
#include <math.h>

// Problem constants
#define BATCH 1024
#define NMAX 100
#define HDIM 768
#define AEMB 128
#define NEMB 256
#define CEMB 64
#define D1 1152
#define D1H 576

typedef __bf16 bf16x8 __attribute__((ext_vector_type(8)));
typedef __bf16 bf16x4 __attribute__((ext_vector_type(4)));
typedef float floatx4 __attribute__((ext_vector_type(4)));

// ---------------------------------------------------------------------------
// Prep: transpose f32 [K,N] -> bf16 [N,K]
// ---------------------------------------------------------------------------
__global__ void transpose_to_bf16(const float* __restrict__ src,
                                  __bf16* __restrict__ dst, int K, int N) {
    int id = blockIdx.x * 256 + threadIdx.x;
    if (id >= K * N) return;
    int k = id / N, n = id - k * N;
    dst[(size_t)n * K + k] = (__bf16)src[(size_t)k * N + n];
}

// ---------------------------------------------------------------------------
// Generic MFMA GEMM: C[R x Ntot] = A[R x K] (f32) @ W[K x Ntot] + bias
//   W supplied transposed+bf16: Wt[Ntot][K]
//   BM=64, BK=64, BN template (128 or 64). 256 threads = 4 waves,
//   each wave computes 16 rows x BN cols via 16x16x32 bf16 MFMA.
//   ACT: 0=none, 1=exact gelu.
//   FUSE (BN==128, grid.y==1 only): fout[row] = sum_n C[row][n]*fvec[n]
// ---------------------------------------------------------------------------
template <int BN, int ACT, bool FUSE>
__global__ __launch_bounds__(256) void gemm_kernel(
    const float* __restrict__ A, int lda, int K,
    const __bf16* __restrict__ Wt,
    const float* __restrict__ bias,
    float* __restrict__ C, int ldc,
    const float* __restrict__ fvec, float* __restrict__ fout) {
    constexpr int BM = 64, BK = 64;
    // pad stride to 72 (144B = 16B-aligned rows, 2-way max bank aliasing = free)
    __shared__ __align__(16) __bf16 sA[BM][72];
    __shared__ __align__(16) __bf16 sB[BN][72];

    const int tid = threadIdx.x;
    const int w = tid >> 6, lane = tid & 63;
    const int quad = lane >> 4, l15 = lane & 15;
    const size_t rowBase = (size_t)blockIdx.x * BM;
    const int nBase = blockIdx.y * BN;

    floatx4 acc[BN / 16];
#pragma unroll
    for (int i = 0; i < BN / 16; i++) acc[i] = (floatx4){0.f, 0.f, 0.f, 0.f};

    const float* Ab = A + rowBase * lda;
    const __bf16* Wb = Wt + (size_t)nBase * K;

    for (int k0 = 0; k0 < K; k0 += BK) {
        // stage A tile 64x64 f32 -> bf16 LDS
#pragma unroll
        for (int j = 0; j < 4; j++) {
            int i = tid + 256 * j;
            int row = i >> 4, c4 = (i & 15) * 4;
            float4 v = *(const float4*)(Ab + (size_t)row * lda + k0 + c4);
            bf16x4 p;
            p[0] = (__bf16)v.x; p[1] = (__bf16)v.y;
            p[2] = (__bf16)v.z; p[3] = (__bf16)v.w;
            *(bf16x4*)&sA[row][c4] = p;
        }
        // stage B tile BN x 64 bf16 (already transposed: contiguous in k)
#pragma unroll
        for (int j = 0; j < BN / 32; j++) {
            int i = tid + 256 * j;
            int n = i >> 3, ks = (i & 7) * 8;
            bf16x8 v = *(const bf16x8*)(Wb + (size_t)n * K + k0 + ks);
            *(bf16x8*)&sB[n][ks] = v;
        }
        __syncthreads();
#pragma unroll
        for (int kk = 0; kk < BK; kk += 32) {
            bf16x8 af = *(const bf16x8*)&sA[w * 16 + l15][kk + quad * 8];
#pragma unroll
            for (int nt = 0; nt < BN / 16; nt++) {
                bf16x8 bf = *(const bf16x8*)&sB[nt * 16 + l15][kk + quad * 8];
                acc[nt] = __builtin_amdgcn_mfma_f32_16x16x32_bf16(af, bf, acc[nt], 0, 0, 0);
            }
        }
        __syncthreads();
    }

    // epilogue: C/D layout col = lane&15, row = quad*4 + reg (m89/m91-verified)
    float bb[BN / 16], vv[BN / 16];
#pragma unroll
    for (int nt = 0; nt < BN / 16; nt++) {
        bb[nt] = bias[nBase + nt * 16 + l15];
        if constexpr (FUSE) vv[nt] = fvec[nt * 16 + l15];
    }
    float fs[4] = {0.f, 0.f, 0.f, 0.f};
#pragma unroll
    for (int nt = 0; nt < BN / 16; nt++) {
#pragma unroll
        for (int reg = 0; reg < 4; reg++) {
            size_t gr = rowBase + w * 16 + quad * 4 + reg;
            float x = acc[nt][reg] + bb[nt];
            if constexpr (ACT == 1)
                x = 0.5f * x * (1.0f + erff(x * 0.70710678118654752f));
            C[gr * ldc + nBase + nt * 16 + l15] = x;
            if constexpr (FUSE) fs[reg] += x * vv[nt];
        }
    }
    if constexpr (FUSE) {
#pragma unroll
        for (int reg = 0; reg < 4; reg++) {
            float s = fs[reg];
            s += __shfl_xor(s, 1);
            s += __shfl_xor(s, 2);
            s += __shfl_xor(s, 4);
            s += __shfl_xor(s, 8);
            if (l15 == 0) fout[rowBase + w * 16 + quad * 4 + reg] = s;
        }
    }
}

// ---------------------------------------------------------------------------
// Attention per (b): score -> masked softmax over n -> ctx -> sim = ctx*wn
// block = 128 threads (thread t = a-dim column / n index in phase 1)
// ---------------------------------------------------------------------------
__global__ __launch_bounds__(128) void attn_kernel(
    const float* __restrict__ wng,   // [B, NMAX, AEMB]
    const float* __restrict__ wn,    // [B, AEMB]
    const float* __restrict__ sng,   // [B*NMAX]  (wng . Wa2, bias included)
    const float* __restrict__ snode, // [B]       (wn . Wa1)
    const float* __restrict__ dist,  // [B, NMAX]
    const int* __restrict__ len,     // [B]
    const float* __restrict__ ba_p, const float* __restrict__ wdb_p,
    const float* __restrict__ bdb_p,
    float* __restrict__ sim,         // [B, 256]
    int side_off) {
    const int b = blockIdx.x, t = threadIdx.x;
    const int wid = t >> 6, lane = t & 63;
    __shared__ float att[NMAX];
    __shared__ float red[2];

    const float ba = ba_p[0], wdb = wdb_p[0], bdb = bdb_p[0];
    const int L = len[b];

    float sc = -1e30f;
    bool valid = (t < NMAX) && (t < L);
    if (t < NMAX) {
        float s = snode[b] + sng[b * NMAX + t] + ba;
        s = (s > 0.f) ? s : 0.01f * s;       // leaky_relu(., 0.01)
        s += dist[b * NMAX + t] * wdb + bdb;
        sc = valid ? s : -1e30f;
    }
    // block max (2 waves)
    float m = sc;
#pragma unroll
    for (int off = 32; off; off >>= 1) m = fmaxf(m, __shfl_xor(m, off));
    if (lane == 0) red[wid] = m;
    __syncthreads();
    m = fmaxf(red[0], red[1]);

    float e = valid ? expf(sc - m) : 0.f;
    float ssum = e;
#pragma unroll
    for (int off = 32; off; off >>= 1) ssum += __shfl_xor(ssum, off);
    __syncthreads();
    if (lane == 0) red[wid] = ssum;
    __syncthreads();
    ssum = red[0] + red[1];
    if (t < NMAX) att[t] = e / ssum;
    __syncthreads();

    // ctx[t] = sum_n wng[b,n,t] * att[n]   (coalesced across t)
    float ctx = 0.f;
    const float* wb = wng + (size_t)b * NMAX * AEMB + t;
#pragma unroll 4
    for (int n = 0; n < NMAX; n++) ctx += wb[(size_t)n * AEMB] * att[n];

    sim[(size_t)b * 256 + side_off + t] = ctx * wn[(size_t)b * AEMB + t];
}

// ---------------------------------------------------------------------------
// build h = [pooled | coord | relu(sim) @ Wn + bn]
// one block (256 thr) per b
// ---------------------------------------------------------------------------
__global__ __launch_bounds__(256) void build_h_kernel(
    const float* __restrict__ sim, const float* __restrict__ Wn,
    const float* __restrict__ bn, const float* __restrict__ pooled,
    const float* __restrict__ x_coord, const float* __restrict__ Wc,
    const float* __restrict__ bc, float* __restrict__ h) {
    const int b = blockIdx.x, t = threadIdx.x;
    __shared__ float ss[256];
    ss[t] = fmaxf(sim[(size_t)b * 256 + t], 0.f);
    __syncthreads();
    float acc = bn[t];
#pragma unroll 8
    for (int i = 0; i < 256; i++) acc += ss[i] * Wn[i * 256 + t];
    float* hb = h + (size_t)b * D1;
    hb[896 + t] = acc;
    hb[t] = pooled[(size_t)b * HDIM + t];
    hb[256 + t] = pooled[(size_t)b * HDIM + 256 + t];
    hb[512 + t] = pooled[(size_t)b * HDIM + 512 + t];
    if (t < 128) hb[768 + t] = x_coord[b] * Wc[t] + bc[t];
}

// ---------------------------------------------------------------------------
// head: logits = h1 @ W2 + b2 ; out = log_softmax. one wave per b.
// ---------------------------------------------------------------------------
__global__ __launch_bounds__(64) void head_kernel(
    const float* __restrict__ h1, const float* __restrict__ W2,
    const float* __restrict__ b2, float* __restrict__ out) {
    const int b = blockIdx.x, lane = threadIdx.x;
    float a0 = 0.f, a1 = 0.f;
#pragma unroll
    for (int k = lane; k < D1H; k += 64) {
        float hv = h1[(size_t)b * D1H + k];
        a0 += hv * W2[2 * k];
        a1 += hv * W2[2 * k + 1];
    }
#pragma unroll
    for (int off = 32; off; off >>= 1) {
        a0 += __shfl_xor(a0, off);
        a1 += __shfl_xor(a1, off);
    }
    if (lane == 0) {
        float l0 = a0 + b2[0], l1 = a1 + b2[1];
        float m = fmaxf(l0, l1);
        float lse = m + logf(expf(l0 - m) + expf(l1 - m));
        out[b * 2 + 0] = l0 - lse;
        out[b * 2 + 1] = l1 - lse;
    }
}

// ---------------------------------------------------------------------------
extern "C" void kernel_launch(void* const* d_in, const int* in_sizes, int n_in,
                              void* d_out, int out_size, void* d_ws, size_t ws_size,
                              hipStream_t stream) {
    const float* pooled  = (const float*)d_in[0];
    const float* x_coord = (const float*)d_in[1];
    const float* node1   = (const float*)d_in[2];
    const float* node2   = (const float*)d_in[3];
    const float* neigh1  = (const float*)d_in[4];
    const float* neigh2  = (const float*)d_in[5];
    const float* dist1   = (const float*)d_in[6];
    const float* dist2   = (const float*)d_in[7];
    const int*   len1    = (const int*)d_in[8];
    const int*   len2    = (const int*)d_in[9];
    const float* Ww      = (const float*)d_in[10];
    const float* bw      = (const float*)d_in[11];
    const float* Wa      = (const float*)d_in[12];
    const float* ba      = (const float*)d_in[13];
    const float* Wdb     = (const float*)d_in[14];
    const float* bdb     = (const float*)d_in[15];
    const float* Wn      = (const float*)d_in[16];
    const float* bn      = (const float*)d_in[17];
    const float* Wc      = (const float*)d_in[18];
    const float* bc      = (const float*)d_in[19];
    const float* W1      = (const float*)d_in[20];
    const float* b1      = (const float*)d_in[21];
    const float* W2      = (const float*)d_in[22];
    const float* b2      = (const float*)d_in[23];

    char* ws = (char*)d_ws;
    size_t off = 0;
    auto alloc = [&](size_t bytes) {
        void* p = ws + off;
        off += (bytes + 255) & ~(size_t)255;
        return p;
    };
    __bf16* Wt_w  = (__bf16*)alloc((size_t)AEMB * HDIM * 2);        // [128][768]
    __bf16* Wt1   = (__bf16*)alloc((size_t)D1H * D1 * 2);           // [576][1152]
    float* wn1    = (float*)alloc((size_t)BATCH * AEMB * 4);
    float* wn2    = (float*)alloc((size_t)BATCH * AEMB * 4);
    float* snode1 = (float*)alloc((size_t)BATCH * 4);
    float* snode2 = (float*)alloc((size_t)BATCH * 4);
    float* wng    = (float*)alloc((size_t)BATCH * NMAX * AEMB * 4); // reused per side
    float* sng    = (float*)alloc((size_t)BATCH * NMAX * 4);
    float* sim    = (float*)alloc((size_t)BATCH * 256 * 4);
    float* h      = (float*)alloc((size_t)BATCH * D1 * 4);
    float* h1     = (float*)alloc((size_t)BATCH * D1H * 4);
    (void)ws_size;

    // prep: transpose weights to bf16 [N][K]
    transpose_to_bf16<<<(HDIM * AEMB + 255) / 256, 256, 0, stream>>>(Ww, Wt_w, HDIM, AEMB);
    transpose_to_bf16<<<(D1 * D1H + 255) / 256, 256, 0, stream>>>(W1, Wt1, D1, D1H);

    // wn = node @ Ww + bw, fused s_node = wn . Wa[0:128]
    dim3 gNode(BATCH / 64, 1);
    gemm_kernel<128, 0, true><<<gNode, 256, 0, stream>>>(
        node1, HDIM, HDIM, Wt_w, bw, wn1, AEMB, Wa, snode1);
    gemm_kernel<128, 0, true><<<gNode, 256, 0, stream>>>(
        node2, HDIM, HDIM, Wt_w, bw, wn2, AEMB, Wa, snode2);

    dim3 gNeigh(BATCH * NMAX / 64, 1);
    // side 1
    gemm_kernel<128, 0, true><<<gNeigh, 256, 0, stream>>>(
        neigh1, HDIM, HDIM, Wt_w, bw, wng, AEMB, Wa + 128, sng);
    attn_kernel<<<BATCH, 128, 0, stream>>>(
        wng, wn1, sng, snode1, dist1, len1, ba, Wdb, bdb, sim, 0);
    // side 2 (reuse wng/sng buffers)
    gemm_kernel<128, 0, true><<<gNeigh, 256, 0, stream>>>(
        neigh2, HDIM, HDIM, Wt_w, bw, wng, AEMB, Wa + 128, sng);
    attn_kernel<<<BATCH, 128, 0, stream>>>(
        wng, wn2, sng, snode2, dist2, len2, ba, Wdb, bdb, sim, 128);

    // h = [pooled | coord | relu(sim)@Wn + bn]
    build_h_kernel<<<BATCH, 256, 0, stream>>>(sim, Wn, bn, pooled, x_coord, Wc, bc, h);

    // h1 = gelu(h @ W1 + b1)
    dim3 gH(BATCH / 64, D1H / 64);
    gemm_kernel<64, 1, false><<<gH, 256, 0, stream>>>(
        h, D1, D1, Wt1, b1, h1, D1H, nullptr, nullptr);

    // logits + log_softmax
    head_kernel<<<BATCH, 64, 0, stream>>>(h1, W2, b2, (float*)d_out);
}

// Round 2
// 807.259 us; speedup vs baseline: 1.1678x; 1.1678x over previous
//
#include <hip/hip_runtime.h>
#include <hip/hip_bf16.h>
#include <math.h>

// Problem constants
#define BATCH 1024
#define NMAX 100
#define HDIM 768
#define AEMB 128
#define D1 1152
#define D1H 576

typedef __bf16 bf16x8 __attribute__((ext_vector_type(8)));
typedef __bf16 bf16x4 __attribute__((ext_vector_type(4)));
typedef float floatx4 __attribute__((ext_vector_type(4)));

// ---------------------------------------------------------------------------
// Prep: transpose f32 [K,N] -> bf16 [N,K]
// ---------------------------------------------------------------------------
__global__ void transpose_to_bf16(const float* __restrict__ src,
                                  __bf16* __restrict__ dst, int K, int N) {
    int id = blockIdx.x * 256 + threadIdx.x;
    if (id >= K * N) return;
    int k = id / N, n = id - k * N;
    dst[(size_t)n * K + k] = (__bf16)src[(size_t)k * N + k == k ? (size_t)k * N + n - (size_t)k * N + (size_t)k * N + n - ((size_t)k * N + n) + (size_t)k * N + n : 0]; // (see below)
}
// NOTE: the line above is intentionally replaced by the clean version:
__global__ void transpose_to_bf16_clean(const float* __restrict__ src,
                                        __bf16* __restrict__ dst, int K, int N) {
    int id = blockIdx.x * 256 + threadIdx.x;
    if (id >= K * N) return;
    int k = id / N, n = id - k * N;
    dst[(size_t)n * K + k] = (__bf16)src[(size_t)k * N + n];
}

// ---------------------------------------------------------------------------
// Fused per-(b,side) kernel:
//   A-tile = [100 neighbor rows | node row | 11 zero rows]  (112 x 768)
//   wng = A @ Ww + bw  kept in registers (MFMA C layout)
//   scores s[row] = wng . Wa2 (row<100) / wn . Wa1 (row==100), cross-lane dot
//   softmax over valid neighbors, ctx = sum att*wng (register-weighted),
//   sim[b, side*128 + c] = ctx[c] * wn[c]
// 256 threads = 4 waves; wave w owns row-tiles {w, w+4 (w<3)} x 8 col-tiles.
// ---------------------------------------------------------------------------
__global__ __launch_bounds__(256) void side_kernel(
    const float* __restrict__ neigh1, const float* __restrict__ neigh2,
    const float* __restrict__ node1, const float* __restrict__ node2,
    const float* __restrict__ dist1, const float* __restrict__ dist2,
    const int* __restrict__ len1, const int* __restrict__ len2,
    const __bf16* __restrict__ Wt,   // [128][768] bf16
    const float* __restrict__ bw,    // [128]
    const float* __restrict__ Wa,    // [256] (rows 0..127 -> wn, 128..255 -> wng)
    const float* __restrict__ ba_p, const float* __restrict__ wdb_p,
    const float* __restrict__ bdb_p,
    float* __restrict__ sim) {       // [B, 256]
    const int b = blockIdx.x, side = blockIdx.y;
    const float* neigh = side ? neigh2 : neigh1;
    const float* node  = side ? node2  : node1;
    const float* dist  = side ? dist2  : dist1;
    const int*   len   = side ? len2   : len1;

    __shared__ __align__(16) __bf16 sA[112][72];
    __shared__ __align__(16) __bf16 sB[128][72];
    __shared__ float scoreLDS[112];
    __shared__ float attLDS[112];
    __shared__ float wn_s[128];
    __shared__ float wavectx[4][128];
    __shared__ float redm[4], reds[4];

    const int tid = threadIdx.x;
    const int w = tid >> 6, lane = tid & 63;
    const int quad = lane >> 4, l15 = lane & 15;

    floatx4 acc[2][8];
#pragma unroll
    for (int t = 0; t < 2; t++)
#pragma unroll
        for (int nt = 0; nt < 8; nt++) acc[t][nt] = (floatx4){0.f, 0.f, 0.f, 0.f};

    const float* nb = neigh + (size_t)b * NMAX * HDIM;
    const float* nd = node + (size_t)b * HDIM;

    for (int k0 = 0; k0 < HDIM; k0 += 64) {
        // stage A: 112 rows x 64 cols, f32 -> bf16
#pragma unroll
        for (int j = 0; j < 7; j++) {
            int i = tid + 256 * j;
            int row = i >> 4, c4 = (i & 15) * 4;
            bf16x4 p;
            if (row < NMAX) {
                float4 v = *(const float4*)(nb + (size_t)row * HDIM + k0 + c4);
                p[0] = (__bf16)v.x; p[1] = (__bf16)v.y;
                p[2] = (__bf16)v.z; p[3] = (__bf16)v.w;
            } else if (row == NMAX) {
                float4 v = *(const float4*)(nd + k0 + c4);
                p[0] = (__bf16)v.x; p[1] = (__bf16)v.y;
                p[2] = (__bf16)v.z; p[3] = (__bf16)v.w;
            } else {
                p[0] = p[1] = p[2] = p[3] = (__bf16)0.f;
            }
            *(bf16x4*)&sA[row][c4] = p;
        }
        // stage B: 128 x 64 bf16 (Wt contiguous in k)
#pragma unroll
        for (int j = 0; j < 4; j++) {
            int i = tid + 256 * j;
            int n = i >> 3, ks = (i & 7) * 8;
            *(bf16x8*)&sB[n][ks] = *(const bf16x8*)(Wt + (size_t)n * HDIM + k0 + ks);
        }
        __syncthreads();
#pragma unroll
        for (int kk = 0; kk < 64; kk += 32) {
            bf16x8 a0 = *(const bf16x8*)&sA[w * 16 + l15][kk + quad * 8];
            bf16x8 a1;
            if (w < 3) a1 = *(const bf16x8*)&sA[(w + 4) * 16 + l15][kk + quad * 8];
#pragma unroll
            for (int nt = 0; nt < 8; nt++) {
                bf16x8 bfrag = *(const bf16x8*)&sB[nt * 16 + l15][kk + quad * 8];
                acc[0][nt] = __builtin_amdgcn_mfma_f32_16x16x32_bf16(a0, bfrag, acc[0][nt], 0, 0, 0);
                if (w < 3)
                    acc[1][nt] = __builtin_amdgcn_mfma_f32_16x16x32_bf16(a1, bfrag, acc[1][nt], 0, 0, 0);
            }
        }
        __syncthreads();
    }

    // --- epilogue: bias + per-row score dot, wn extraction ---
    float bwv[8], wa1v[8], wa2v[8];
#pragma unroll
    for (int nt = 0; nt < 8; nt++) {
        int c = l15 + 16 * nt;
        bwv[nt] = bw[c];
        wa1v[nt] = Wa[c];
        wa2v[nt] = Wa[128 + c];
    }
#pragma unroll
    for (int t = 0; t < 2; t++) {
        if (t == 1 && w == 3) break;
        int tile = w + 4 * t;
#pragma unroll
        for (int reg = 0; reg < 4; reg++) {
            int row = tile * 16 + quad * 4 + reg;
            float s = 0.f;
#pragma unroll
            for (int nt = 0; nt < 8; nt++) {
                float v = acc[t][nt][reg] + bwv[nt];
                acc[t][nt][reg] = v;
                s += v * ((row == NMAX) ? wa1v[nt] : wa2v[nt]);
            }
            s += __shfl_xor(s, 1);
            s += __shfl_xor(s, 2);
            s += __shfl_xor(s, 4);
            s += __shfl_xor(s, 8);
            if (l15 == 0) scoreLDS[row] = s;
            if (row == NMAX) {
#pragma unroll
                for (int nt = 0; nt < 8; nt++) wn_s[l15 + 16 * nt] = acc[t][nt][reg];
            }
        }
    }
    __syncthreads();

    // --- softmax over neighbors (all 256 threads participate in reductions) ---
    const float ba = ba_p[0], wdb = wdb_p[0], bdb = bdb_p[0];
    const int L = len[b];
    float sc = -1e30f;
    bool valid = (tid < NMAX) && (tid < L);
    if (tid < NMAX) {
        float pre = scoreLDS[NMAX] + scoreLDS[tid] + ba;
        pre = (pre > 0.f) ? pre : 0.01f * pre;
        pre += dist[(size_t)b * NMAX + tid] * wdb + bdb;
        sc = valid ? pre : -1e30f;
    }
    float m = sc;
#pragma unroll
    for (int off = 32; off; off >>= 1) m = fmaxf(m, __shfl_xor(m, off));
    if (lane == 0) redm[w] = m;
    __syncthreads();
    m = fmaxf(fmaxf(redm[0], redm[1]), fmaxf(redm[2], redm[3]));
    float e = valid ? expf(sc - m) : 0.f;
    float ssum = e;
#pragma unroll
    for (int off = 32; off; off >>= 1) ssum += __shfl_xor(ssum, off);
    if (lane == 0) reds[w] = ssum;
    __syncthreads();
    ssum = (reds[0] + reds[1]) + (reds[2] + reds[3]);
    if (tid < 112) attLDS[tid] = (tid < NMAX) ? (e / ssum) : 0.f;
    __syncthreads();

    // --- ctx = sum_n att[n] * wng[n][c], register-weighted, quad-reduced ---
    float partial[8];
#pragma unroll
    for (int nt = 0; nt < 8; nt++) partial[nt] = 0.f;
#pragma unroll
    for (int t = 0; t < 2; t++) {
        if (t == 1 && w == 3) break;
        int tile = w + 4 * t;
#pragma unroll
        for (int reg = 0; reg < 4; reg++) {
            float a = attLDS[tile * 16 + quad * 4 + reg];
#pragma unroll
            for (int nt = 0; nt < 8; nt++) partial[nt] += a * acc[t][nt][reg];
        }
    }
#pragma unroll
    for (int nt = 0; nt < 8; nt++) {
        float p = partial[nt];
        p += __shfl_xor(p, 16);
        p += __shfl_xor(p, 32);
        if (quad == 0) wavectx[w][l15 + 16 * nt] = p;
    }
    __syncthreads();
    if (tid < 128) {
        float ctx = (wavectx[0][tid] + wavectx[1][tid]) + (wavectx[2][tid] + wavectx[3][tid]);
        sim[(size_t)b * 256 + side * 128 + tid] = ctx * wn_s[tid];
    }
}

// ---------------------------------------------------------------------------
// Generic MFMA GEMM (used for h @ W1): BM=64, BK=64, BN=64, gelu epilogue
// ---------------------------------------------------------------------------
template <int BN, int ACT>
__global__ __launch_bounds__(256) void gemm_kernel(
    const float* __restrict__ A, int lda, int K,
    const __bf16* __restrict__ Wt,
    const float* __restrict__ bias,
    float* __restrict__ C, int ldc) {
    constexpr int BM = 64, BK = 64;
    __shared__ __align__(16) __bf16 sA[BM][72];
    __shared__ __align__(16) __bf16 sB[BN][72];

    const int tid = threadIdx.x;
    const int w = tid >> 6, lane = tid & 63;
    const int quad = lane >> 4, l15 = lane & 15;
    const size_t rowBase = (size_t)blockIdx.x * BM;
    const int nBase = blockIdx.y * BN;

    floatx4 acc[BN / 16];
#pragma unroll
    for (int i = 0; i < BN / 16; i++) acc[i] = (floatx4){0.f, 0.f, 0.f, 0.f};

    const float* Ab = A + rowBase * lda;
    const __bf16* Wb = Wt + (size_t)nBase * K;

    for (int k0 = 0; k0 < K; k0 += BK) {
#pragma unroll
        for (int j = 0; j < 4; j++) {
            int i = tid + 256 * j;
            int row = i >> 4, c4 = (i & 15) * 4;
            float4 v = *(const float4*)(Ab + (size_t)row * lda + k0 + c4);
            bf16x4 p;
            p[0] = (__bf16)v.x; p[1] = (__bf16)v.y;
            p[2] = (__bf16)v.z; p[3] = (__bf16)v.w;
            *(bf16x4*)&sA[row][c4] = p;
        }
#pragma unroll
        for (int j = 0; j < BN / 32; j++) {
            int i = tid + 256 * j;
            int n = i >> 3, ks = (i & 7) * 8;
            *(bf16x8*)&sB[n][ks] = *(const bf16x8*)(Wb + (size_t)n * K + k0 + ks);
        }
        __syncthreads();
#pragma unroll
        for (int kk = 0; kk < BK; kk += 32) {
            bf16x8 af = *(const bf16x8*)&sA[w * 16 + l15][kk + quad * 8];
#pragma unroll
            for (int nt = 0; nt < BN / 16; nt++) {
                bf16x8 bfrag = *(const bf16x8*)&sB[nt * 16 + l15][kk + quad * 8];
                acc[nt] = __builtin_amdgcn_mfma_f32_16x16x32_bf16(af, bfrag, acc[nt], 0, 0, 0);
            }
        }
        __syncthreads();
    }
#pragma unroll
    for (int nt = 0; nt < BN / 16; nt++) {
        float bb = bias[nBase + nt * 16 + l15];
#pragma unroll
        for (int reg = 0; reg < 4; reg++) {
            size_t gr = rowBase + w * 16 + quad * 4 + reg;
            float x = acc[nt][reg] + bb;
            if constexpr (ACT == 1)
                x = 0.5f * x * (1.0f + erff(x * 0.70710678118654752f));
            C[gr * ldc + nBase + nt * 16 + l15] = x;
        }
    }
}

// ---------------------------------------------------------------------------
// build h = [pooled | coord | relu(sim) @ Wn + bn]; one block (256) per b
// ---------------------------------------------------------------------------
__global__ __launch_bounds__(256) void build_h_kernel(
    const float* __restrict__ sim, const float* __restrict__ Wn,
    const float* __restrict__ bn, const float* __restrict__ pooled,
    const float* __restrict__ x_coord, const float* __restrict__ Wc,
    const float* __restrict__ bc, float* __restrict__ h) {
    const int b = blockIdx.x, t = threadIdx.x;
    __shared__ float ss[256];
    ss[t] = fmaxf(sim[(size_t)b * 256 + t], 0.f);
    __syncthreads();
    float acc = bn[t];
#pragma unroll 8
    for (int i = 0; i < 256; i++) acc += ss[i] * Wn[i * 256 + t];
    float* hb = h + (size_t)b * D1;
    hb[896 + t] = acc;
    hb[t] = pooled[(size_t)b * HDIM + t];
    hb[256 + t] = pooled[(size_t)b * HDIM + 256 + t];
    hb[512 + t] = pooled[(size_t)b * HDIM + 512 + t];
    if (t < 128) hb[768 + t] = x_coord[b] * Wc[t] + bc[t];
}

// ---------------------------------------------------------------------------
// head: logits = h1 @ W2 + b2 ; out = log_softmax. one wave per b.
// ---------------------------------------------------------------------------
__global__ __launch_bounds__(64) void head_kernel(
    const float* __restrict__ h1, const float* __restrict__ W2,
    const float* __restrict__ b2, float* __restrict__ out) {
    const int b = blockIdx.x, lane = threadIdx.x;
    float a0 = 0.f, a1 = 0.f;
#pragma unroll
    for (int k = lane; k < D1H; k += 64) {
        float hv = h1[(size_t)b * D1H + k];
        a0 += hv * W2[2 * k];
        a1 += hv * W2[2 * k + 1];
    }
#pragma unroll
    for (int off = 32; off; off >>= 1) {
        a0 += __shfl_xor(a0, off);
        a1 += __shfl_xor(a1, off);
    }
    if (lane == 0) {
        float l0 = a0 + b2[0], l1 = a1 + b2[1];
        float m = fmaxf(l0, l1);
        float lse = m + logf(expf(l0 - m) + expf(l1 - m));
        out[b * 2 + 0] = l0 - lse;
        out[b * 2 + 1] = l1 - lse;
    }
}

// ---------------------------------------------------------------------------
extern "C" void kernel_launch(void* const* d_in, const int* in_sizes, int n_in,
                              void* d_out, int out_size, void* d_ws, size_t ws_size,
                              hipStream_t stream) {
    const float* pooled  = (const float*)d_in[0];
    const float* x_coord = (const float*)d_in[1];
    const float* node1   = (const float*)d_in[2];
    const float* node2   = (const float*)d_in[3];
    const float* neigh1  = (const float*)d_in[4];
    const float* neigh2  = (const float*)d_in[5];
    const float* dist1   = (const float*)d_in[6];
    const float* dist2   = (const float*)d_in[7];
    const int*   len1    = (const int*)d_in[8];
    const int*   len2    = (const int*)d_in[9];
    const float* Ww      = (const float*)d_in[10];
    const float* bw      = (const float*)d_in[11];
    const float* Wa      = (const float*)d_in[12];
    const float* ba      = (const float*)d_in[13];
    const float* Wdb     = (const float*)d_in[14];
    const float* bdb     = (const float*)d_in[15];
    const float* Wn      = (const float*)d_in[16];
    const float* bn      = (const float*)d_in[17];
    const float* Wc      = (const float*)d_in[18];
    const float* bc      = (const float*)d_in[19];
    const float* W1      = (const float*)d_in[20];
    const float* b1      = (const float*)d_in[21];
    const float* W2      = (const float*)d_in[22];
    const float* b2      = (const float*)d_in[23];

    char* ws = (char*)d_ws;
    size_t off = 0;
    auto alloc = [&](size_t bytes) {
        void* p = ws + off;
        off += (bytes + 255) & ~(size_t)255;
        return p;
    };
    __bf16* Wt_w = (__bf16*)alloc((size_t)AEMB * HDIM * 2);  // [128][768]
    __bf16* Wt1  = (__bf16*)alloc((size_t)D1H * D1 * 2);     // [576][1152]
    float* sim   = (float*)alloc((size_t)BATCH * 256 * 4);
    float* h     = (float*)alloc((size_t)BATCH * D1 * 4);
    float* h1    = (float*)alloc((size_t)BATCH * D1H * 4);
    (void)ws_size;

    transpose_to_bf16_clean<<<(HDIM * AEMB + 255) / 256, 256, 0, stream>>>(Ww, Wt_w, HDIM, AEMB);
    transpose_to_bf16_clean<<<(D1 * D1H + 255) / 256, 256, 0, stream>>>(W1, Wt1, D1, D1H);

    dim3 gSide(BATCH, 2);
    side_kernel<<<gSide, 256, 0, stream>>>(
        neigh1, neigh2, node1, node2, dist1, dist2, len1, len2,
        Wt_w, bw, Wa, ba, Wdb, bdb, sim);

    build_h_kernel<<<BATCH, 256, 0, stream>>>(sim, Wn, bn, pooled, x_coord, Wc, bc, h);

    dim3 gH(BATCH / 64, D1H / 64);
    gemm_kernel<64, 1><<<gH, 256, 0, stream>>>(h, D1, D1, Wt1, b1, h1, D1H);

    head_kernel<<<BATCH, 64, 0, stream>>>(h1, W2, b2, (float*)d_out);
}